// Round 23
// baseline (106.204 us; speedup 1.0000x reference)
//
#include <hip/hip_runtime.h>
#include <math.h>

#define BB 2
#define CC 128
#define NQ 200
#define NQP 224      // padded to 7 tiles of 32
#define KK 24000
#define NH 8
#define DH 16
#define NCAM 16
#define NFFN 256

#define NSEG 50      // k-segments for split-K flash (700 blocks: 1 generation)
#define TPS 15       // 32-key tiles per segment (50*15*32 = 24000)
#define NGRP (BB*NSEG)   // 100 (b,seg) groups
#define SLOTX 13         // ceil(NGRP/8) groups per XCD

#define TK 32        // keys per chain block (small quantum: low regs/LDS -> high residency)
#define NPS (BB*NQP)     // 448 post_self blocks (dispatched first in merged kernel)
#define NQB (BB*NQ)      // 400 query rows

#define LOG2E 1.44269504f

#if __has_builtin(__builtin_amdgcn_exp2f)
#define EXP2(x) __builtin_amdgcn_exp2f(x)
#else
#define EXP2(x) exp2f(x)
#endif

// ---- workspace float-region offsets ----
#define O_MU    0
#define O_RSTD  16
#define O_SINV  32
#define O_CP    1024                             // cam partials [256][2]
#define O_Q0    2048
#define O_QPE   (O_Q0  + BB*NQ*CC)
#define O_XS    (O_QPE + BB*NQ*CC)
#define O_SQ    (O_XS  + BB*NQ*CC)
#define O_SK    (O_SQ  + BB*NQ*CC)
#define O_SV    (O_SK  + BB*NQ*CC)
#define O_SO    (O_SV  + BB*NQ*CC)
#define O_X1    (O_SO  + BB*NQ*CC)
#define O_OH    (O_X1  + BB*NQ*CC)
#define O_PART  (O_OH  + BB*NQ*CC)               // [B*H][NSEG][NQP][18] (17 used: l, acc16)
#define O_BF    (O_PART + BB*NH*NSEG*NQP*18)     // bf16 region starts here

// ---- bf16 (ushort) region offsets ----
#define U_KH   0                                  // khH: [B][H][K][16] bf16 (head-major)
#define U_VH   (BB*KK*CC)                         // vhH: [B][H][K/32][16][32] bf16 (1KB tiles)
#define U_FT   (2*BB*KK*CC)                       // (unused, layout kept)
#define U_CT   (3*BB*KK*CC)                       // (unused)
#define U_W    (3*BB*KK*CC + BB*KK*32)            // weights: frag-ordered [128][32] + 6x[128][128]
#define U_QW   (U_W + 4096 + 6*16384)             // qwU [B][NQP][C] bf16 (x0.25*log2e folded)
#define U_ONES (U_QW + BB*NQP*CC)                 // [KK+64] bf16 ones (PV row-sum trick)
#define U_WX   (U_ONES + KK + 64)                 // Wck2 = Wk_pos2 @ Wck, frag order [128][128]

typedef __attribute__((ext_vector_type(8))) short bfrag8;
typedef __attribute__((ext_vector_type(4))) float f32x4;
typedef __attribute__((ext_vector_type(16))) float f32x16;

__device__ __forceinline__ unsigned short f2bf(float x) {
    unsigned u = __float_as_uint(x);
    u += 0x7fffu + ((u >> 16) & 1u);
    return (unsigned short)(u >> 16);
}
__device__ __forceinline__ float bf2f(unsigned short h) {
    return __uint_as_float(((unsigned)h) << 16);
}
__device__ __forceinline__ unsigned cvtpk_bf16(float lo, float hi) {
    unsigned r;
    asm volatile("v_cvt_pk_bf16_f32 %0, %1, %2" : "=v"(r) : "v"(lo), "v"(hi));
    return r;
}
__device__ __forceinline__ void pl32swap(unsigned &a, unsigned &b) {
    asm volatile("v_permlane32_swap_b32 %0, %1" : "+v"(a), "+v"(b));
}

// LayerNorm over 128 values held by threads t<128, safe for 512-thread blocks.
__device__ __forceinline__ float lnorm512(float x, int t, float* rs, float* rs2, float* col) {
    if (t < 128) { rs[t] = x; rs2[t] = x*x; }
    __syncthreads();
    if (t < 64) {
        float v  = rs[t]  + rs[t+64];
        float v2 = rs2[t] + rs2[t+64];
#pragma unroll
        for (int off = 32; off > 0; off >>= 1) {
            v  += __shfl_down(v,  off);
            v2 += __shfl_down(v2, off);
        }
        if (t == 0) { col[0] = v; col[1] = v2; }
    }
    __syncthreads();
    float mean = col[0] * (1.0f/128.0f);
    float var  = col[1] * (1.0f/128.0f) - mean*mean;
    return (x - mean) * rsqrtf(var + 1e-5f);
}

// ============================ k_pre: cam partials + weights + ones + QUERY + Wck2 ============================

__global__ __launch_bounds__(512) void k_pre(
    const float* __restrict__ cam,
    const float* __restrict__ cw2, const float* __restrict__ cw3,
    const float* __restrict__ proj, const float* __restrict__ k2,
    const float* __restrict__ ck,  const float* __restrict__ cv,
    const float* __restrict__ cw1,
    unsigned short* __restrict__ wtU, unsigned short* __restrict__ onesU,
    unsigned short* __restrict__ wxU,
    float* __restrict__ ws,
    const float* __restrict__ qf, const float* __restrict__ qpos,
    const float* __restrict__ qsize,
    const float* __restrict__ Wpq, const float* __restrict__ Wp1,
    const float* __restrict__ Wp2,
    const float* __restrict__ Wsq, const float* __restrict__ Wsk,
    const float* __restrict__ Wsv)
{
    __shared__ float r1[256], r2[256];
    __shared__ float qrow[CC], ph[CC], xsr[CC], q0r[CC];
    __shared__ float pA[4*132], pB[4*132], pC[4*132];
    __shared__ float wckL[128*16];
    int t = threadIdx.x;
    if (blockIdx.x < 256) {
        int blk = blockIdx.x;
        int r = blk >> 3;
        int s = blk & 7;
        const float* src = cam + (size_t)r*KK + s*3000;
        float sm = 0.f, s2 = 0.f;
        if (t < 256)
            for (int i = t; i < 3000; i += 256) { float v = src[i]; sm += v; s2 += v*v; }
        if (t < 256) { r1[t] = sm; r2[t] = s2; }
        __syncthreads();
        for (int off = 128; off > 0; off >>= 1) {
            if (t < off) { r1[t] += r1[t+off]; r2[t] += r2[t+off]; }
            __syncthreads();
        }
        if (t == 0) { ws[O_CP + blk*2] = r1[0]; ws[O_CP + blk*2 + 1] = r2[0]; }
    } else if (blockIdx.x < 264) {
        int blk = blockIdx.x - 256;
        if (blk < 6) {
            const float* W = (blk==0)?cw2:(blk==1)?cw3:(blk==2)?proj:(blk==3)?k2:(blk==4)?ck:cv;
            unsigned short* dst = wtU + 4096 + blk*16384;
            for (int i = t; i < 16384; i += 512) {
                int j = i & 7, lx = (i >> 3) & 63, cs = (i >> 9) & 3, w16 = i >> 11;
                int d = w16*16 + (lx & 15);
                int c = cs*32 + (lx >> 4)*8 + j;
                dst[i] = f2bf(W[c*CC + d]);
            }
        } else if (blk == 6) {
            for (int i = t; i < 4096; i += 512) {
                int j = i & 7, lx = (i >> 3) & 63, w16 = i >> 9;
                int d = w16*16 + (lx & 15);
                int c = (lx >> 4)*8 + j;
                wtU[i] = (c < 16) ? f2bf(cw1[c*CC + d]) : (unsigned short)0;
            }
        } else {
            for (int i = t; i < KK + 64; i += 512) onesU[i] = 0x3F80;  // bf16 1.0
        }
    } else if (blockIdx.x < 264 + NQB) {
        // query: proj + pos-emb + self-QKV (512-thr, 4-way K-split)
        int row = blockIdx.x - 264;          // b*NQ + n
        int b = row / NQ, n = row - b*NQ;
        int d = t & 127, p = t >> 7;
        if (t < CC) {
            qrow[t] = qf[((size_t)b*CC + t)*NQ + n];
            float px = qpos[row*2], py = qpos[row*2+1];
            ph[t] = fmaxf(px*Wp1[t] + py*Wp1[CC+t], 0.f);
        }
        if (t < 2) {
            float sg = qsize[row*2 + t]*0.5f + 0.01f;
            ws[O_SINV + row*2 + t] = LOG2E / (2.f * sg * sg);
        }
        __syncthreads();
        {
            float aQ = 0.f, aP = 0.f;
            int c0 = p*32;
#pragma unroll
            for (int c = 0; c < 32; c++) {
                aQ = fmaf(qrow[c0+c], Wpq[(c0+c)*CC + d], aQ);
                aP = fmaf(ph[c0+c],   Wp2[(c0+c)*CC + d], aP);
            }
            pA[p*132 + d] = aQ; pB[p*132 + d] = aP;
        }
        __syncthreads();
        if (t < CC) {
            float q0 = (pA[t] + pA[132+t]) + (pA[264+t] + pA[396+t]);
            float pe = (pB[t] + pB[132+t]) + (pB[264+t] + pB[396+t]);
            ws[O_Q0  + row*CC + t] = q0;
            ws[O_QPE + row*CC + t] = pe;
            q0r[t] = q0;
            xsr[t] = q0 + pe;
        }
        __syncthreads();
        {
            float a = 0.f, k2v = 0.f, v2 = 0.f;
            int c0 = p*32;
#pragma unroll
            for (int c = 0; c < 32; c++) {
                float xv = xsr[c0+c], qv = q0r[c0+c];
                a   = fmaf(xv, Wsq[(c0+c)*CC + d], a);
                k2v = fmaf(xv, Wsk[(c0+c)*CC + d], k2v);
                v2  = fmaf(qv, Wsv[(c0+c)*CC + d], v2);
            }
            pA[p*132 + d] = a; pB[p*132 + d] = k2v; pC[p*132 + d] = v2;
        }
        __syncthreads();
        if (t < CC) {
            ws[O_SQ + row*CC + t] = (pA[t] + pA[132+t]) + (pA[264+t] + pA[396+t]);
            ws[O_SK + row*CC + t] = (pB[t] + pB[132+t]) + (pB[264+t] + pB[396+t]);
            ws[O_SV + row*CC + t] = (pC[t] + pC[132+t]) + (pC[264+t] + pC[396+t]);
        }
    } else {
        // Wck2 = Wk_pos2 @ Wck for d-slice w16; output frag-ordered into wxU.
        int w16 = blockIdx.x - (264 + NQB);  // 0..7
        {
            int e = t >> 2, i0 = (t & 3) * 4;
#pragma unroll
            for (int i = 0; i < 4; i++)
                wckL[e*16 + i0 + i] = ck[(size_t)e*CC + w16*16 + i0 + i];
        }
        __syncthreads();
        {
            int c = t >> 2, dls = (t & 3) * 4;
            const float* wrow = k2 + (size_t)c*CC;
            float acc[4] = {0.f, 0.f, 0.f, 0.f};
            for (int e = 0; e < 128; e++) {
                float w = wrow[e];
#pragma unroll
                for (int i = 0; i < 4; i++)
                    acc[i] = fmaf(w, wckL[e*16 + dls + i], acc[i]);
            }
            int cs = c >> 5, j = c & 7, lhi = ((c >> 3) & 3) * 16;
#pragma unroll
            for (int i = 0; i < 4; i++) {
                int lane = lhi + (dls + i);
                wxU[((w16*4 + cs) << 9) + lane*8 + j] = f2bf(acc[i]);
            }
        }
    }
}

// ============================ chain helpers (fragment-ordered X tiles, 2 kt tiles) ============================
// X tile = 32 keys x 128 cols stored as [kt][cs][lane][8] (lane = g*16+m):
// a wave's B-frag read is 1KB contiguous: X + (kt*4+cs)*512 + l*8.

__device__ __forceinline__ int frag_col(int d0, int m) {
    return ((((d0 >> 5) * 4 + ((d0 >> 3) & 3)) * 16 + m) << 3) + (d0 & 7);
}

__device__ __forceinline__ void ld_a4h(bfrag8 a[4], const unsigned short* __restrict__ Wf,
                                       int w16, int l) {
#pragma unroll
    for (int cs = 0; cs < 4; cs++)
        a[cs] = *(const bfrag8*)(Wf + ((w16*4 + cs) << 9) + l*8);
}

__device__ __forceinline__ void mfma_apply4h(const unsigned short* __restrict__ X,
                                             const bfrag8 a[4],
                                             int l, f32x4 acc[2])
{
    const f32x4 z = {0.f, 0.f, 0.f, 0.f};
#pragma unroll
    for (int kt = 0; kt < 2; kt++) acc[kt] = z;
#pragma unroll
    for (int kt = 0; kt < 2; kt++)
#pragma unroll
        for (int cs = 0; cs < 4; cs++) {
            bfrag8 bf = *(const bfrag8*)(X + ((kt*4 + cs) << 9) + l*8);
            acc[kt] = __builtin_amdgcn_mfma_f32_16x16x32_bf16(a[cs], bf, acc[kt], 0, 0, 0);
        }
}

__device__ __forceinline__ void mfma_acc4h(const unsigned short* __restrict__ X,
                                           const bfrag8 a[4],
                                           int l, f32x4 acc[2])
{
#pragma unroll
    for (int kt = 0; kt < 2; kt++)
#pragma unroll
        for (int cs = 0; cs < 4; cs++) {
            bfrag8 bf = *(const bfrag8*)(X + ((kt*4 + cs) << 9) + l*8);
            acc[kt] = __builtin_amdgcn_mfma_f32_16x16x32_bf16(a[cs], bf, acc[kt], 0, 0, 0);
        }
}

__device__ __forceinline__ void mfma_apply1h(const unsigned short* __restrict__ X,
                                             bfrag8 a1, int l, f32x4 acc[2])
{
    const f32x4 z = {0.f, 0.f, 0.f, 0.f};
#pragma unroll
    for (int kt = 0; kt < 2; kt++) acc[kt] = z;
#pragma unroll
    for (int kt = 0; kt < 2; kt++) {
        bfrag8 bf = *(const bfrag8*)(X + (kt << 11) + l*8);
        acc[kt] = __builtin_amdgcn_mfma_f32_16x16x32_bf16(a1, bf, acc[kt], 0, 0, 0);
    }
}

template<bool RELU>
__device__ __forceinline__ void store_tiles_h(unsigned short* __restrict__ Xd,
                                              const f32x4 acc[2], int m, int g, int dbase)
{
    int cp = frag_col(dbase + g*4, m);
#pragma unroll
    for (int kt = 0; kt < 2; kt++) {
        ushort4 pk;
        float v0 = acc[kt][0], v1 = acc[kt][1], v2 = acc[kt][2], v3 = acc[kt][3];
        if (RELU) { v0 = fmaxf(v0,0.f); v1 = fmaxf(v1,0.f); v2 = fmaxf(v2,0.f); v3 = fmaxf(v3,0.f); }
        pk.x = f2bf(v0); pk.y = f2bf(v1); pk.z = f2bf(v2); pk.w = f2bf(v3);
        *(ushort4*)(Xd + (kt << 11) + cp) = pk;
    }
}

// ============================ merged chain + post_self (post_self blocks FIRST) ============================

__global__ __launch_bounds__(512) void k_chainps(
    const float* __restrict__ key_feat, const float* __restrict__ cam_info,
    const float* __restrict__ key_pos, const float* __restrict__ Wk1,
    const unsigned short* __restrict__ wtU, const unsigned short* __restrict__ wxU,
    unsigned short* __restrict__ khH, unsigned short* __restrict__ vhH,
    const float* __restrict__ Wso, const float* __restrict__ Wcq,
    unsigned short* __restrict__ qwU,
    float* __restrict__ ws)
{
    __shared__ __align__(16) union SM {
        struct {
            unsigned short XA[4096];
            unsigned short XB[4096];
            float w1buf[256];
            float kpx[TK], kpy[TK];
            float cmu[NCAM], crs[NCAM];
        } c;
        struct {
            float sor[CC], qcr[CC], sq[CC];
            float part[4*132];
            float rs[CC], rs2[CC], col[2];
        } s;
    } sm;

    int t = threadIdx.x;

    if (blockIdx.x < NPS) {
        // ------------- post_self path (with fused self-attention) -------------
        int row = blockIdx.x;               // b*NQP + n
        int b = row / NQP, n = row - b*NQP;
        if (n >= NQ) { if (t < CC) qwU[(size_t)row*CC + t] = 0; return; }
        int rw = b*NQ + n;
        int d = t & 127, p = t >> 7;
        float* sor = sm.s.sor;
        float* qcr = sm.s.qcr;
        float* sq  = sm.s.sq;
        float* part = sm.s.part;
        float* rs = sm.s.rs;
        float* rs2 = sm.s.rs2;
        float* col = sm.s.col;

        if (t < CC) sq[t] = ws[O_SQ + (size_t)rw*CC + t];
        __syncthreads();

        // fused self-attn: head h = wave, keys lane-parallel
        {
            int h = t >> 6;       // 0..7
            int l = t & 63;
            float qv[16];
#pragma unroll
            for (int j = 0; j < 16; j++) qv[j] = sq[h*16 + j];
            float s[4], pexp[4];
            float mloc = -1e30f;
#pragma unroll
            for (int w2 = 0; w2 < 4; w2++) {
                int k = l + w2*64;
                float sv = -1e30f;
                if (k < NQ) {
                    const float* kr = ws + O_SK + ((size_t)(b*NQ + k))*CC + h*16;
                    float a2 = 0.f;
#pragma unroll
                    for (int j = 0; j < 16; j += 4) {
                        float4 kv = *(const float4*)(kr + j);
                        a2 += qv[j]*kv.x + qv[j+1]*kv.y + qv[j+2]*kv.z + qv[j+3]*kv.w;
                    }
                    sv = a2 * 0.25f;
                }
                s[w2] = sv;
                mloc = fmaxf(mloc, sv);
            }
#pragma unroll
            for (int off = 32; off > 0; off >>= 1) mloc = fmaxf(mloc, __shfl_xor(mloc, off));
            float lsum = 0.f;
#pragma unroll
            for (int w2 = 0; w2 < 4; w2++) {
                pexp[w2] = (s[w2] > -1e29f) ? __expf(s[w2] - mloc) : 0.f;
                lsum += pexp[w2];
            }
#pragma unroll
            for (int off = 32; off > 0; off >>= 1) lsum += __shfl_xor(lsum, off);
            float o[16];
#pragma unroll
            for (int j = 0; j < 16; j++) o[j] = 0.f;
#pragma unroll
            for (int w2 = 0; w2 < 4; w2++) {
                int k = l + w2*64;
                if (k < NQ) {
                    const float* vr = ws + O_SV + ((size_t)(b*NQ + k))*CC + h*16;
                    float pw = pexp[w2];
#pragma unroll
                    for (int j = 0; j < 16; j += 4) {
                        float4 vv = *(const float4*)(vr + j);
                        o[j]   = fmaf(pw, vv.x, o[j]);
                        o[j+1] = fmaf(pw, vv.y, o[j+1]);
                        o[j+2] = fmaf(pw, vv.z, o[j+2]);
                        o[j+3] = fmaf(pw, vv.w, o[j+3]);
                    }
                }
            }
#pragma unroll
            for (int j = 0; j < 16; j++) {
#pragma unroll
                for (int off = 32; off > 0; off >>= 1) o[j] += __shfl_xor(o[j], off);
            }
            if (l == 0) {
                float inv = 1.f / lsum;
#pragma unroll
                for (int j = 0; j < 16; j++) sor[h*16 + j] = o[j] * inv;
            }
        }
        __syncthreads();

        // Wso GEMV + LN + Wcq GEMV
        {
            float acc = 0.f;
            int c0 = p*32;
#pragma unroll
            for (int c = 0; c < 32; c++) acc = fmaf(sor[c0+c], Wso[(c0+c)*CC + d], acc);
            part[p*132 + d] = acc;
        }
        __syncthreads();
        float x = 0.f;
        if (t < CC) x = ws[O_Q0 + rw*CC + t] + ((part[t] + part[132+t]) + (part[264+t] + part[396+t]));
        x = lnorm512(x, t, rs, rs2, col);
        if (t < CC) {
            ws[O_X1 + rw*CC + t] = x;
            qcr[t] = x + ws[O_QPE + rw*CC + t];
        }
        __syncthreads();
        {
            float acc = 0.f;
            int c0 = p*32;
#pragma unroll
            for (int c = 0; c < 32; c++) acc = fmaf(qcr[c0+c], Wcq[(c0+c)*CC + d], acc);
            part[p*132 + d] = acc;
        }
        __syncthreads();
        if (t < CC) {
            float qh = (part[t] + part[132+t]) + (part[264+t] + part[396+t]);
            qwU[(size_t)row*CC + t] = f2bf(0.25f * LOG2E * qh);
        }
        return;
    }

    // ------------- chain path (TK=32, 8 waves, one 16-d slice/wave) -------------
    unsigned short* XA = sm.c.XA;
    unsigned short* XB = sm.c.XB;
    float* w1buf = sm.c.w1buf;
    float* kpx = sm.c.kpx;
    float* kpy = sm.c.kpy;
    float* cmu = sm.c.cmu;
    float* crs = sm.c.crs;

    int blk = blockIdx.x - NPS;
    int b = blk / (KK/TK);
    int k0 = (blk - b*(KK/TK)) * TK;
    int l = t & 63;
    int m = l & 15, g = l >> 4;
    int w16 = t >> 6;                 // 0..7 = d-slice = head
    int dbase = w16 * 16;

    const unsigned short* WT_CW1  = wtU;
    const unsigned short* WT_CW2  = wtU + 4096;
    const unsigned short* WT_CW3  = wtU + 4096 + 16384;
    const unsigned short* WT_PROJ = wtU + 4096 + 2*16384;
    const unsigned short* WT_CK   = wtU + 4096 + 4*16384;
    const unsigned short* WT_CV   = wtU + 4096 + 5*16384;

    // cam_fin fused: recompute mu/rstd from the 256 partials
    if (t < NCAM) {
        float S = 0.f, S2 = 0.f;
#pragma unroll
        for (int bb2 = 0; bb2 < BB; bb2++)
#pragma unroll
            for (int s = 0; s < 8; s++) {
                int blk2 = ((bb2*NCAM + t) << 3) | s;
                S  += ws[O_CP + blk2*2];
                S2 += ws[O_CP + blk2*2 + 1];
            }
        float mu  = S * (1.0f/(BB*KK));
        float var = S2 * (1.0f/(BB*KK)) - mu*mu;
        cmu[t] = mu;
        crs[t] = rsqrtf(var + 1e-5f);
    }
    __syncthreads();

    if (t < 128) {
        // stage normalized cam -> XA (frag order): c = t>>3 in 0..15, 4 keys each
        int c = t >> 3;
        int kq = (t & 7) * 4;
        float4 v = *(const float4*)(cam_info + ((size_t)b*NCAM + c)*KK + k0 + kq);
        float mu = cmu[c], rsd = crs[c];
        int ktb = (kq >> 4) << 11;
        int cb  = frag_col(c & ~7, 0) + (c & 7);
        XA[ktb + cb + ((kq  ) & 15)*8] = f2bf((v.x - mu)*rsd);
        XA[ktb + cb + ((kq+1) & 15)*8] = f2bf((v.y - mu)*rsd);
        XA[ktb + cb + ((kq+2) & 15)*8] = f2bf((v.z - mu)*rsd);
        XA[ktb + cb + ((kq+3) & 15)*8] = f2bf((v.w - mu)*rsd);
    } else if (t < 256) {
        // zero cols 16..31 of cs=0 for both kt tiles: 128 ushort4
        int tz = t - 128;
        int kt = tz >> 6, r = tz & 63;
        int gz = 2 + (r >> 5), mz = (r >> 1) & 15, j4 = (r & 1) * 4;
        ushort4 z4 = make_ushort4(0,0,0,0);
        *(ushort4*)(XA + (kt << 11) + (gz*16 + mz)*8 + j4) = z4;
    }
    if (t < 256) w1buf[t] = Wk1[t];
    if (t < TK) {
        float2 p = ((const float2*)key_pos)[b*KK + k0 + t];
        kpx[t] = p.x; kpy[t] = p.y;
    }

    // prologue A-frag loads: L1 + prefetch L2
    bfrag8 a1 = *(const bfrag8*)(WT_CW1 + (w16 << 9) + l*8);
    bfrag8 aA[4], aB[4], aC[4];
    ld_a4h(aA, WT_CW2, w16, l);
    __syncthreads();

    f32x4 acc[2];

    // L1: h1 = relu(cb @ cw1)
    mfma_apply1h(XA, a1, l, acc);
    store_tiles_h<true>(XB, acc, m, g, dbase);
    __syncthreads();
    ld_a4h(aB, WT_CW3, w16, l);          // prefetch L3

    // L2: h2 = relu(h1 @ cw2)
    mfma_apply4h(XB, aA, l, acc);
    store_tiles_h<true>(XA, acc, m, g, dbase);
    __syncthreads();
    ld_a4h(aA, WT_PROJ, w16, l);         // prefetch L4

    // stage key_feat -> XB (frag order, overlaps L3); L3: gate = sigmoid(h2 @ cw3)
    {
        int c = t >> 2, q4 = t & 3;      // 8 keys per thread (2 float4)
        const float* src = key_feat + ((size_t)b*CC + c)*KK + k0 + q4*8;
        int cb = frag_col(c & ~7, 0) + (c & 7);
#pragma unroll
        for (int qq = 0; qq < 2; qq++) {
            float4 v = ((const float4*)src)[qq];
            int kk = q4*8 + qq*4;
            int base = ((kk >> 4) << 11) + cb;
            XB[base + ((kk  ) & 15)*8] = f2bf(v.x);
            XB[base + ((kk+1) & 15)*8] = f2bf(v.y);
            XB[base + ((kk+2) & 15)*8] = f2bf(v.z);
            XB[base + ((kk+3) & 15)*8] = f2bf(v.w);
        }
    }
    mfma_apply4h(XA, aB, l, acc);
    float garr[2][4];
#pragma unroll
    for (int kt = 0; kt < 2; kt++)
#pragma unroll
        for (int r = 0; r < 4; r++)
            garr[kt][r] = 1.f / (1.f + __expf(-acc[kt][r]));
    __syncthreads();

    // L4: kf = (feat @ Wproj_k) * gate -> XA
    mfma_apply4h(XB, aA, l, acc);
#pragma unroll
    for (int kt = 0; kt < 2; kt++)
#pragma unroll
        for (int r = 0; r < 4; r++)
            acc[kt][r] *= garr[kt][r];
    store_tiles_h<false>(XA, acc, m, g, dbase);
    __syncthreads();
    ld_a4h(aA, WT_CV, w16, l);           // A-frags for vh

    // ph = relu(pos @ Wk_pos1) -> XB (frag order, one 16B store per thread)
    {
        int k = t >> 4, dq = (t & 15) * 8;   // k 0..31, 8 cols per thread
        int ktb = (k >> 4) << 11;
        int mk = k & 15;
        float px = kpx[k], py = kpy[k];
        union { unsigned short u[8]; bfrag8 f; } cA;
#pragma unroll
        for (int j = 0; j < 8; j++)
            cA.u[j] = f2bf(fmaxf(px*w1buf[dq+j] + py*w1buf[128+dq+j], 0.f));
        *(bfrag8*)(XB + ktb + frag_col(dq, mk)) = cA.f;
    }
    __syncthreads();

    // vh = kf @ Wcv  (then reuse aA's registers)
    mfma_apply4h(XA, aA, l, acc);
#pragma unroll
    for (int kt = 0; kt < 2; kt++) {
        int k = k0 + kt*16 + m;
        size_t tb = ((size_t)(b*NH + w16)*(KK/32) + (k >> 5))*512 + (k & 31);
#pragma unroll
        for (int r = 0; r < 4; r++)
            vhH[tb + (g*4 + r)*32] = f2bf(acc[kt][r]);
    }
    ld_a4h(aA, WT_CK, w16, l);           // A-frags for kh (kf part)
    ld_a4h(aC, wxU, w16, l);             // A-frags for kh (ph part, Wck2)

    // kh = kf@Wck + ph@Wck2 -> head-major khH[b][h][k][16]
    mfma_apply4h(XA, aA, l, acc);
    mfma_acc4h(XB, aC, l, acc);
#pragma unroll
    for (int kt = 0; kt < 2; kt++) {
        int k = k0 + kt*16 + m;
        ushort4 pk;
        pk.x = f2bf(acc[kt][0]); pk.y = f2bf(acc[kt][1]);
        pk.z = f2bf(acc[kt][2]); pk.w = f2bf(acc[kt][3]);
        *(ushort4*)(khH + (((size_t)(b*NH + w16)*KK + k) << 4) + g*4) = pk;
    }
}

// ============================ MFMA flash cross-attention ============================

struct KPRegs { float4 r[8]; };

__device__ __forceinline__ void kp_read(KPRegs& kp, const float4* __restrict__ f4, int fb) {
#pragma unroll
    for (int mm = 0; mm < 4; mm++) {
        kp.r[2*mm]   = f4[fb + 4*mm];
        kp.r[2*mm+1] = f4[fb + 4*mm + 1];
    }
}
__device__ __forceinline__ void kp_bias(f32x16& bias, const KPRegs& kp,
                                        float qx, float qy, float nsx, float nsy) {
#pragma unroll
    for (int mm = 0; mm < 4; mm++) {
        float4 c0 = kp.r[2*mm], c1 = kp.r[2*mm+1];
        float dx, dy;
        dx = c0.x - qx; dy = c0.y - qy; bias[4*mm+0] = fmaf(dy*dy, nsy, dx*dx*nsx);
        dx = c0.z - qx; dy = c0.w - qy; bias[4*mm+1] = fmaf(dy*dy, nsy, dx*dx*nsx);
        dx = c1.x - qx; dy = c1.y - qy; bias[4*mm+2] = fmaf(dy*dy, nsy, dx*dx*nsx);
        dx = c1.z - qx; dy = c1.w - qy; bias[4*mm+3] = fmaf(dy*dy, nsy, dx*dx*nsx);
    }
}

__device__ __forceinline__ void flash_head(
    const f32x16& s, f32x16& acc, bfrag8 vfa, bfrag8 vfb)
{
    float p[16];
#pragma unroll
    for (int i = 0; i < 16; i++) p[i] = EXP2(s[i]);
    unsigned pk[8];
#pragma unroll
    for (int mm = 0; mm < 4; mm++) {
        pk[2*mm]   = cvtpk_bf16(p[4*mm],   p[4*mm+1]);
        pk[2*mm+1] = cvtpk_bf16(p[4*mm+2], p[4*mm+3]);
    }
    {
        unsigned a0 = pk[0], b0 = pk[2];
        unsigned a1 = pk[1], b1 = pk[3];
        pl32swap(a0, b0);
        pl32swap(a1, b1);
        union { unsigned u[4]; bfrag8 f; } pf;
        pf.u[0] = a0; pf.u[1] = a1; pf.u[2] = b0; pf.u[3] = b1;
        acc = __builtin_amdgcn_mfma_f32_32x32x16_bf16(vfa, pf.f, acc, 0, 0, 0);
    }
    {
        unsigned a0 = pk[4], b0 = pk[6];
        unsigned a1 = pk[5], b1 = pk[7];
        pl32swap(a0, b0);
        pl32swap(a1, b1);
        union { unsigned u[4]; bfrag8 f; } pf;
        pf.u[0] = a0; pf.u[1] = a1; pf.u[2] = b0; pf.u[3] = b1;
        acc = __builtin_amdgcn_mfma_f32_32x32x16_bf16(vfb, pf.f, acc, 0, 0, 0);
    }
}

__global__ __launch_bounds__(256) void k_flash(
    const float* __restrict__ qpos, const float* __restrict__ key_pos,
    const unsigned short* __restrict__ khH, const unsigned short* __restrict__ vhH,
    const unsigned short* __restrict__ qwU, const unsigned short* __restrict__ onesU,
    float* __restrict__ ws)
{
    // XCD-group swizzle: SLOTX groups per XCD
    int id = blockIdx.x;
    int slot = id >> 3;
    int group = (id & 7) * SLOTX + slot / 7;
    if (group >= NGRP) return;
    int qt  = slot % 7;
    int b   = group / NSEG;
    int seg = group - b*NSEG;

    int wv  = threadIdx.x >> 6;
    int l   = threadIdx.x & 63;
    int lq  = l & 31;
    int g   = l >> 5;
    int h0  = wv*2, h1 = h0 + 1;
    int q   = qt*32 + lq;
    int qc  = min(q, NQ-1);
    int t   = threadIdx.x;

    __shared__ __align__(16) float kpbuf[TPS*32*2];

    int kt0 = seg * (TPS*32);
    {
        const float4* src = (const float4*)(key_pos + ((size_t)b*KK + kt0)*2);
        for (int i = t; i < TPS*32/2; i += 256)
            ((float4*)kpbuf)[i] = src[i];
    }

    float qx  = qpos[(b*NQ+qc)*2], qy = qpos[(b*NQ+qc)*2+1];
    float nsx = -ws[O_SINV + (b*NQ+qc)*2];
    float nsy = -ws[O_SINV + (b*NQ+qc)*2+1];

    const unsigned short* qrow = qwU + ((size_t)b*NQP + q)*CC + g*8;
    bfrag8 qf0 = *(const bfrag8*)(qrow + h0*DH);
    bfrag8 qf1 = *(const bfrag8*)(qrow + h1*DH);

    const unsigned short* kb0 = khH + (((size_t)(b*NH + h0)*KK + lq) << 4) + g*8;
    const unsigned short* kb1 = khH + (((size_t)(b*NH + h1)*KK + lq) << 4) + g*8;
    bool isOnes = (lq == 16);
    const unsigned short* vt0 = vhH + (size_t)(b*NH + h0)*(KK/32)*512 + (lq & 15)*32 + g*8;
    const unsigned short* vt1 = vhH + (size_t)(b*NH + h1)*(KK/32)*512 + (lq & 15)*32 + g*8;
    const unsigned short* on8 = onesU + g*8;

    f32x16 acc0, acc1;
#pragma unroll
    for (int i = 0; i < 16; i++) { acc0[i] = 0.f; acc1[i] = 0.f; }

    int tile0 = kt0 >> 5;
    bfrag8 kf0 = *(const bfrag8*)(kb0 + ((size_t)kt0 << 4));
    bfrag8 kf1 = *(const bfrag8*)(kb1 + ((size_t)kt0 << 4));
    bfrag8 vc00 = isOnes ? *(const bfrag8*)on8 : *(const bfrag8*)(vt0 + (size_t)tile0*512);
    bfrag8 vc01 = isOnes ? *(const bfrag8*)on8 : *(const bfrag8*)(vt0 + (size_t)tile0*512 + 16);
    bfrag8 vc10 = isOnes ? *(const bfrag8*)on8 : *(const bfrag8*)(vt1 + (size_t)tile0*512);
    bfrag8 vc11 = isOnes ? *(const bfrag8*)on8 : *(const bfrag8*)(vt1 + (size_t)tile0*512 + 16);

    __syncthreads();

    const float4* kpf4 = (const float4*)kpbuf;
    KPRegs kpn;
    kp_read(kpn, kpf4, 2*g);
    f32x16 bias;
    kp_bias(bias, kpn, qx, qy, nsx, nsy);

    for (int it = 0; it < TPS; it++) {
        int itn = (it+1 < TPS) ? it+1 : it;
        int kn = kt0 + itn*32;
        int tn = kn >> 5;
        bfrag8 kf0n = *(const bfrag8*)(kb0 + ((size_t)kn << 4));
        bfrag8 kf1n = *(const bfrag8*)(kb1 + ((size_t)kn << 4));
        bfrag8 vn00 = isOnes ? *(const bfrag8*)on8 : *(const bfrag8*)(vt0 + (size_t)tn*512);
        bfrag8 vn01 = isOnes ? *(const bfrag8*)on8 : *(const bfrag8*)(vt0 + (size_t)tn*512 + 16);
        bfrag8 vn10 = isOnes ? *(const bfrag8*)on8 : *(const bfrag8*)(vt1 + (size_t)tn*512);
        bfrag8 vn11 = isOnes ? *(const bfrag8*)on8 : *(const bfrag8*)(vt1 + (size_t)tn*512 + 16);
        kp_read(kpn, kpf4, itn*16 + 2*g);

        f32x16 s0 = __builtin_amdgcn_mfma_f32_32x32x16_bf16(kf0, qf0, bias, 0, 0, 0);
        f32x16 s1 = __builtin_amdgcn_mfma_f32_32x32x16_bf16(kf1, qf1, bias, 0, 0, 0);

        flash_head(s0, acc0, vc00, vc01);
        flash_head(s1, acc1, vc10, vc11);

        kp_bias(bias, kpn, qx, qy, nsx, nsy);
        kf0 = kf0n; kf1 = kf1n;
        vc00 = vn00; vc01 = vn01; vc10 = vn10; vc11 = vn11;
    }

    {
        float* o = ws + O_PART + (((size_t)(b*NH + h0)*NSEG + seg)*NQP + q)*18;
        if (l < 32) o[0] = acc0[8];
#pragma unroll
        for (int rr = 0; rr < 8; rr++) o[1 + (rr&3) + 8*(rr>>2) + 4*g] = acc0[rr];
    }
    {
        float* o = ws + O_PART + (((size_t)(b*NH + h1)*NSEG + seg)*NQP + q)*18;
        if (l < 32) o[0] = acc1[8];
#pragma unroll
        for (int rr = 0; rr < 8; rr++) o[1 + (rr&3) + 8*(rr>>2) + 4*g] = acc1[rr];
    }
}

// ============================ combine + Wco + LN + FFN + LN (fused, 512-thr seg-split) ============================

__global__ __launch_bounds__(512) void k_final(
    const float* __restrict__ Wco, const float* __restrict__ W1,
    const float* __restrict__ b1f, const float* __restrict__ W2,
    const float* __restrict__ b2f, float* __restrict__ ws,
    float* __restrict__ out)
{
    int row = blockIdx.x;               // b*NQ + q
    int b = row / NQ, q = row - b*NQ;
    int t = threadIdx.x;
    int d = t & 127, p = t >> 7;
    __shared__ float orow[CC], x1r[CC], x2r[CC], hrr[NFFN];
    __shared__ float part[4*132];
    __shared__ float part2[2*260];
    __shared__ float rs[CC], rs2[CC], col[2];
    __shared__ float lpart[32], Lh[8];

    // combine: 4-way seg-split sums over PART (fixed-max softmax => plain sums)
    {
        int h = d >> 4, j = d & 15;
        const float* pb = ws + O_PART + (((size_t)(b*NH + h)*NSEG)*NQP + q)*18;
        int s0 = p*13, s1 = (s0 + 13 < NSEG) ? s0 + 13 : NSEG;
        float sA = 0.f, sL = 0.f;
        for (int sg = s0; sg < s1; sg++) {
            const float* pp = pb + (size_t)sg*(NQP*18);
            sA += pp[1 + j];
            if (j == 0) sL += pp[0];
        }
        part[p*132 + d] = sA;
        if (j == 0) lpart[p*8 + h] = sL;
    }
    if (t < CC) x1r[t] = ws[O_X1 + (size_t)row*CC + t];
    __syncthreads();
    if (t < 8) Lh[t] = (lpart[t] + lpart[8+t]) + (lpart[16+t] + lpart[24+t]);
    __syncthreads();
    if (t < CC)
        orow[t] = ((part[t] + part[132+t]) + (part[264+t] + part[396+t])) / Lh[t >> 4];
    __syncthreads();

    {
        float acc = 0.f;
        int c0 = p*32;
#pragma unroll
        for (int c = 0; c < 32; c++) acc = fmaf(orow[c0+c], Wco[(c0+c)*CC + d], acc);
        part[p*132 + d] = acc;
    }
    __syncthreads();
    float x = 0.f;
    if (t < CC) x = x1r[t] + ((part[t] + part[132+t]) + (part[264+t] + part[396+t]));
    x = lnorm512(x, t, rs, rs2, col);
    if (t < CC) x2r[t] = x;
    __syncthreads();
    {
        int o = t & 255, ph2 = t >> 8;
        float h = 0.f;
        int c0 = ph2*64;
#pragma unroll 16
        for (int c = 0; c < 64; c++) h = fmaf(x2r[c0+c], W1[(c0+c)*NFFN + o], h);
        part2[ph2*260 + o] = h;
    }
    __syncthreads();
    if (t < NFFN) hrr[t] = fmaxf(part2[t] + part2[260+t] + b1f[t], 0.f);
    __syncthreads();
    {
        float acc = 0.f;
        int f0 = p*64;
#pragma unroll 16
        for (int f = 0; f < 64; f++) acc = fmaf(hrr[f0+f], W2[(f0+f)*CC + d], acc);
        part[p*132 + d] = acc;
    }
    __syncthreads();
    float y = 0.f;
    if (t < CC) y = x2r[t] + b2f[t] + ((part[t] + part[132+t]) + (part[264+t] + part[396+t]));
    y = lnorm512(y, t, rs, rs2, col);
    if (t < CC) out[(size_t)row*CC + t] = y;
}

// ============================ launch ============================

extern "C" void kernel_launch(void* const* d_in, const int* in_sizes, int n_in,
                              void* d_out, int out_size, void* d_ws, size_t ws_size,
                              hipStream_t stream)
{
    const float* query_feat = (const float*)d_in[0];
    const float* key_feat   = (const float*)d_in[1];
    const float* query_pos  = (const float*)d_in[2];
    const float* key_pos    = (const float*)d_in[3];
    const float* query_size = (const float*)d_in[4];
    const float* cam_info   = (const float*)d_in[5];
    const float* Wproj_q = (const float*)d_in[6];
    const float* Wproj_k = (const float*)d_in[7];
    const float* Wq_pos1 = (const float*)d_in[8];
    const float* Wq_pos2 = (const float*)d_in[9];
    const float* Wk_pos1 = (const float*)d_in[10];
    const float* Wk_pos2 = (const float*)d_in[11];
    const float* Wsq = (const float*)d_in[12];
    const float* Wsk = (const float*)d_in[13];
    const float* Wsv = (const float*)d_in[14];
    const float* Wso = (const float*)d_in[15];
    const float* Wcq = (const float*)d_in[16];
    const float* Wck = (const float*)d_in[17];
    const float* Wcv = (const float*)d_in[18];
    const float* Wco = (const float*)d_in[19];
    const float* Wffn1 = (const float*)d_in[20];
    const float* bffn1 = (const float*)d_in[21];
    const float* Wffn2 = (const float*)d_in[22];
    const float* bffn2 = (const float*)d_in[23];
    const float* cam_w1 = (const float*)d_in[24];
    const float* cam_w2 = (const float*)d_in[25];
    const float* cam_w3 = (const float*)d_in[26];
    float* ws  = (float*)d_ws;
    float* out = (float*)d_out;
    unsigned short* wsu = (unsigned short*)(ws + O_BF);
    unsigned short* khH = wsu + U_KH;
    unsigned short* vhH = wsu + U_VH;
    unsigned short* wtU = wsu + U_W;
    unsigned short* qwU = wsu + U_QW;
    unsigned short* onU = wsu + U_ONES;
    unsigned short* wxU = wsu + U_WX;

    hipLaunchKernelGGL(k_pre, dim3(264 + NQB + 8), dim3(512), 0, stream,
        cam_info, cam_w2, cam_w3, Wproj_k, Wk_pos2, Wck, Wcv, cam_w1, wtU, onU, wxU, ws,
        query_feat, query_pos, query_size, Wproj_q, Wq_pos1, Wq_pos2, Wsq, Wsk, Wsv);
    hipLaunchKernelGGL(k_chainps, dim3(NPS + BB*KK/TK), dim3(512), 0, stream,
        key_feat, cam_info, key_pos, Wk_pos1, wtU, wxU, khH, vhH, Wso, Wcq, qwU, ws);
    hipLaunchKernelGGL(k_flash, dim3(8*SLOTX*7), dim3(256), 0, stream,
        query_pos, key_pos, khH, vhH, qwU, onU, ws);
    hipLaunchKernelGGL(k_final, dim3(BB*NQ), dim3(512), 0, stream,
        Wco, Wffn1, bffn1, Wffn2, bffn2, ws, out);
}

// Round 24
// 103.631 us; speedup vs baseline: 1.0248x; 1.0248x over previous
//
#include <hip/hip_runtime.h>
#include <math.h>

#define BB 2
#define CC 128
#define NQ 200
#define NQP 224      // padded to 7 tiles of 32
#define KK 24000
#define NH 8
#define DH 16
#define NCAM 16
#define NFFN 256

#define NSEG 50      // k-segments for split-K flash (700 blocks: 1 generation)
#define TPS 15       // 32-key tiles per segment (50*15*32 = 24000)
#define NGRP (BB*NSEG)   // 100 (b,seg) groups
#define SLOTX 13         // ceil(NGRP/8) groups per XCD

#define TK 64        // keys per chain block
#define NPS (BB*NQP)     // 448 post_self blocks (dispatched first in merged kernel)
#define NQB (BB*NQ)      // 400 query rows

#define LOG2E 1.44269504f

#if __has_builtin(__builtin_amdgcn_exp2f)
#define EXP2(x) __builtin_amdgcn_exp2f(x)
#else
#define EXP2(x) exp2f(x)
#endif

// ---- workspace float-region offsets ----
#define O_MU    0
#define O_RSTD  16
#define O_SINV  32
#define O_CP    1024                             // cam partials [256][2]
#define O_Q0    2048
#define O_QPE   (O_Q0  + BB*NQ*CC)
#define O_XS    (O_QPE + BB*NQ*CC)
#define O_SQ    (O_XS  + BB*NQ*CC)
#define O_SK    (O_SQ  + BB*NQ*CC)
#define O_SV    (O_SK  + BB*NQ*CC)
#define O_SO    (O_SV  + BB*NQ*CC)
#define O_X1    (O_SO  + BB*NQ*CC)
#define O_OH    (O_X1  + BB*NQ*CC)
#define O_PART  (O_OH  + BB*NQ*CC)               // [B*H][NSEG][NQP][18] (17 used: l, acc16)
#define O_BF    (O_PART + BB*NH*NSEG*NQP*18)     // bf16 region starts here

// ---- bf16 (ushort) region offsets ----
#define U_KH   0                                  // khH: [B][H][K][16] bf16 (head-major)
#define U_VH   (BB*KK*CC)                         // vhH: [B][H][K/32][16][32] bf16 (1KB tiles)
#define U_FT   (2*BB*KK*CC)                       // (unused, layout kept)
#define U_CT   (3*BB*KK*CC)                       // (unused)
#define U_W    (3*BB*KK*CC + BB*KK*32)            // weights: frag-ordered [128][32] + 6x[128][128]
#define U_QW   (U_W + 4096 + 6*16384)             // qwU [B][NQP][C] bf16 (x0.25*log2e folded)
#define U_ONES (U_QW + BB*NQP*CC)                 // [KK+64] bf16 ones (PV row-sum trick)
#define U_WX   (U_ONES + KK + 64)                 // Wck2 = Wk_pos2 @ Wck, frag order [128][128]

typedef __attribute__((ext_vector_type(8))) short bfrag8;
typedef __attribute__((ext_vector_type(4))) float f32x4;
typedef __attribute__((ext_vector_type(16))) float f32x16;

__device__ __forceinline__ unsigned short f2bf(float x) {
    unsigned u = __float_as_uint(x);
    u += 0x7fffu + ((u >> 16) & 1u);
    return (unsigned short)(u >> 16);
}
__device__ __forceinline__ float bf2f(unsigned short h) {
    return __uint_as_float(((unsigned)h) << 16);
}
__device__ __forceinline__ unsigned cvtpk_bf16(float lo, float hi) {
    unsigned r;
    asm volatile("v_cvt_pk_bf16_f32 %0, %1, %2" : "=v"(r) : "v"(lo), "v"(hi));
    return r;
}
__device__ __forceinline__ void pl32swap(unsigned &a, unsigned &b) {
    asm volatile("v_permlane32_swap_b32 %0, %1" : "+v"(a), "+v"(b));
}

// LayerNorm over 128 values held by threads t<128, safe for 512-thread blocks.
__device__ __forceinline__ float lnorm512(float x, int t, float* rs, float* rs2, float* col) {
    if (t < 128) { rs[t] = x; rs2[t] = x*x; }
    __syncthreads();
    if (t < 64) {
        float v  = rs[t]  + rs[t+64];
        float v2 = rs2[t] + rs2[t+64];
#pragma unroll
        for (int off = 32; off > 0; off >>= 1) {
            v  += __shfl_down(v,  off);
            v2 += __shfl_down(v2, off);
        }
        if (t == 0) { col[0] = v; col[1] = v2; }
    }
    __syncthreads();
    float mean = col[0] * (1.0f/128.0f);
    float var  = col[1] * (1.0f/128.0f) - mean*mean;
    return (x - mean) * rsqrtf(var + 1e-5f);
}

// ============================ k_pre: cam partials + weights + ones + QUERY + Wck2 ============================

__global__ __launch_bounds__(512) void k_pre(
    const float* __restrict__ cam,
    const float* __restrict__ cw2, const float* __restrict__ cw3,
    const float* __restrict__ proj, const float* __restrict__ k2,
    const float* __restrict__ ck,  const float* __restrict__ cv,
    const float* __restrict__ cw1,
    unsigned short* __restrict__ wtU, unsigned short* __restrict__ onesU,
    unsigned short* __restrict__ wxU,
    float* __restrict__ ws,
    const float* __restrict__ qf, const float* __restrict__ qpos,
    const float* __restrict__ qsize,
    const float* __restrict__ Wpq, const float* __restrict__ Wp1,
    const float* __restrict__ Wp2,
    const float* __restrict__ Wsq, const float* __restrict__ Wsk,
    const float* __restrict__ Wsv)
{
    __shared__ float r1[256], r2[256];
    __shared__ float qrow[CC], ph[CC], xsr[CC], q0r[CC];
    __shared__ float pA[4*132], pB[4*132], pC[4*132];
    __shared__ float wckL[128*16];
    int t = threadIdx.x;
    if (blockIdx.x < 256) {
        int blk = blockIdx.x;
        int r = blk >> 3;
        int s = blk & 7;
        const float* src = cam + (size_t)r*KK + s*3000;
        float sm = 0.f, s2 = 0.f;
        if (t < 256)
            for (int i = t; i < 3000; i += 256) { float v = src[i]; sm += v; s2 += v*v; }
        if (t < 256) { r1[t] = sm; r2[t] = s2; }
        __syncthreads();
        for (int off = 128; off > 0; off >>= 1) {
            if (t < off) { r1[t] += r1[t+off]; r2[t] += r2[t+off]; }
            __syncthreads();
        }
        if (t == 0) { ws[O_CP + blk*2] = r1[0]; ws[O_CP + blk*2 + 1] = r2[0]; }
    } else if (blockIdx.x < 264) {
        int blk = blockIdx.x - 256;
        if (blk < 6) {
            const float* W = (blk==0)?cw2:(blk==1)?cw3:(blk==2)?proj:(blk==3)?k2:(blk==4)?ck:cv;
            unsigned short* dst = wtU + 4096 + blk*16384;
            for (int i = t; i < 16384; i += 512) {
                int j = i & 7, lx = (i >> 3) & 63, cs = (i >> 9) & 3, w16 = i >> 11;
                int d = w16*16 + (lx & 15);
                int c = cs*32 + (lx >> 4)*8 + j;
                dst[i] = f2bf(W[c*CC + d]);
            }
        } else if (blk == 6) {
            for (int i = t; i < 4096; i += 512) {
                int j = i & 7, lx = (i >> 3) & 63, w16 = i >> 9;
                int d = w16*16 + (lx & 15);
                int c = (lx >> 4)*8 + j;
                wtU[i] = (c < 16) ? f2bf(cw1[c*CC + d]) : (unsigned short)0;
            }
        } else {
            for (int i = t; i < KK + 64; i += 512) onesU[i] = 0x3F80;  // bf16 1.0
        }
    } else if (blockIdx.x < 264 + NQB) {
        // query: proj + pos-emb + self-QKV (512-thr, 4-way K-split)
        int row = blockIdx.x - 264;          // b*NQ + n
        int b = row / NQ, n = row - b*NQ;
        int d = t & 127, p = t >> 7;
        if (t < CC) {
            qrow[t] = qf[((size_t)b*CC + t)*NQ + n];
            float px = qpos[row*2], py = qpos[row*2+1];
            ph[t] = fmaxf(px*Wp1[t] + py*Wp1[CC+t], 0.f);
        }
        if (t < 2) {
            float sg = qsize[row*2 + t]*0.5f + 0.01f;
            ws[O_SINV + row*2 + t] = LOG2E / (2.f * sg * sg);
        }
        __syncthreads();
        {
            float aQ = 0.f, aP = 0.f;
            int c0 = p*32;
#pragma unroll
            for (int c = 0; c < 32; c++) {
                aQ = fmaf(qrow[c0+c], Wpq[(c0+c)*CC + d], aQ);
                aP = fmaf(ph[c0+c],   Wp2[(c0+c)*CC + d], aP);
            }
            pA[p*132 + d] = aQ; pB[p*132 + d] = aP;
        }
        __syncthreads();
        if (t < CC) {
            float q0 = (pA[t] + pA[132+t]) + (pA[264+t] + pA[396+t]);
            float pe = (pB[t] + pB[132+t]) + (pB[264+t] + pB[396+t]);
            ws[O_Q0  + row*CC + t] = q0;
            ws[O_QPE + row*CC + t] = pe;
            q0r[t] = q0;
            xsr[t] = q0 + pe;
        }
        __syncthreads();
        {
            float a = 0.f, k2v = 0.f, v2 = 0.f;
            int c0 = p*32;
#pragma unroll
            for (int c = 0; c < 32; c++) {
                float xv = xsr[c0+c], qv = q0r[c0+c];
                a   = fmaf(xv, Wsq[(c0+c)*CC + d], a);
                k2v = fmaf(xv, Wsk[(c0+c)*CC + d], k2v);
                v2  = fmaf(qv, Wsv[(c0+c)*CC + d], v2);
            }
            pA[p*132 + d] = a; pB[p*132 + d] = k2v; pC[p*132 + d] = v2;
        }
        __syncthreads();
        if (t < CC) {
            ws[O_SQ + row*CC + t] = (pA[t] + pA[132+t]) + (pA[264+t] + pA[396+t]);
            ws[O_SK + row*CC + t] = (pB[t] + pB[132+t]) + (pB[264+t] + pB[396+t]);
            ws[O_SV + row*CC + t] = (pC[t] + pC[132+t]) + (pC[264+t] + pC[396+t]);
        }
    } else {
        // Wck2 = Wk_pos2 @ Wck for d-slice w16; output frag-ordered into wxU.
        int w16 = blockIdx.x - (264 + NQB);  // 0..7
        {
            int e = t >> 2, i0 = (t & 3) * 4;
#pragma unroll
            for (int i = 0; i < 4; i++)
                wckL[e*16 + i0 + i] = ck[(size_t)e*CC + w16*16 + i0 + i];
        }
        __syncthreads();
        {
            int c = t >> 2, dls = (t & 3) * 4;
            const float* wrow = k2 + (size_t)c*CC;
            float acc[4] = {0.f, 0.f, 0.f, 0.f};
            for (int e = 0; e < 128; e++) {
                float w = wrow[e];
#pragma unroll
                for (int i = 0; i < 4; i++)
                    acc[i] = fmaf(w, wckL[e*16 + dls + i], acc[i]);
            }
            int cs = c >> 5, j = c & 7, lhi = ((c >> 3) & 3) * 16;
#pragma unroll
            for (int i = 0; i < 4; i++) {
                int lane = lhi + (dls + i);
                wxU[((w16*4 + cs) << 9) + lane*8 + j] = f2bf(acc[i]);
            }
        }
    }
}

// ============================ chain helpers (fragment-ordered X tiles) ============================
// X tile = 64 keys x 128 cols stored as [kt][cs][lane][8] (lane = g*16+m),
// so a wave's B-frag read is 1KB contiguous: X + (kt*4+cs)*512 + l*8.

__device__ __forceinline__ int frag_col(int d0, int m) {
    return ((((d0 >> 5) * 4 + ((d0 >> 3) & 3)) * 16 + m) << 3) + (d0 & 7);
}

__device__ __forceinline__ void ld_a4h(bfrag8 a[4], const unsigned short* __restrict__ Wf,
                                       int w16, int l) {
#pragma unroll
    for (int cs = 0; cs < 4; cs++)
        a[cs] = *(const bfrag8*)(Wf + ((w16*4 + cs) << 9) + l*8);
}

__device__ __forceinline__ void mfma_apply4h(const unsigned short* __restrict__ X,
                                             const bfrag8 a[4],
                                             int l, f32x4 acc[4])
{
    const f32x4 z = {0.f, 0.f, 0.f, 0.f};
#pragma unroll
    for (int kt = 0; kt < 4; kt++) acc[kt] = z;
#pragma unroll
    for (int kt = 0; kt < 4; kt++)
#pragma unroll
        for (int cs = 0; cs < 4; cs++) {
            bfrag8 bf = *(const bfrag8*)(X + ((kt*4 + cs) << 9) + l*8);
            acc[kt] = __builtin_amdgcn_mfma_f32_16x16x32_bf16(a[cs], bf, acc[kt], 0, 0, 0);
        }
}

__device__ __forceinline__ void mfma_acc4h(const unsigned short* __restrict__ X,
                                           const bfrag8 a[4],
                                           int l, f32x4 acc[4])
{
#pragma unroll
    for (int kt = 0; kt < 4; kt++)
#pragma unroll
        for (int cs = 0; cs < 4; cs++) {
            bfrag8 bf = *(const bfrag8*)(X + ((kt*4 + cs) << 9) + l*8);
            acc[kt] = __builtin_amdgcn_mfma_f32_16x16x32_bf16(a[cs], bf, acc[kt], 0, 0, 0);
        }
}

__device__ __forceinline__ void mfma_apply1h(const unsigned short* __restrict__ X,
                                             bfrag8 a1, int l, f32x4 acc[4])
{
    const f32x4 z = {0.f, 0.f, 0.f, 0.f};
#pragma unroll
    for (int kt = 0; kt < 4; kt++) acc[kt] = z;
#pragma unroll
    for (int kt = 0; kt < 4; kt++) {
        bfrag8 bf = *(const bfrag8*)(X + (kt << 11) + l*8);
        acc[kt] = __builtin_amdgcn_mfma_f32_16x16x32_bf16(a1, bf, acc[kt], 0, 0, 0);
    }
}

template<bool RELU>
__device__ __forceinline__ void store_tiles_h(unsigned short* __restrict__ Xd,
                                              const f32x4 acc[4], int m, int g, int dbase)
{
    int cp = frag_col(dbase + g*4, m);
#pragma unroll
    for (int kt = 0; kt < 4; kt++) {
        ushort4 pk;
        float v0 = acc[kt][0], v1 = acc[kt][1], v2 = acc[kt][2], v3 = acc[kt][3];
        if (RELU) { v0 = fmaxf(v0,0.f); v1 = fmaxf(v1,0.f); v2 = fmaxf(v2,0.f); v3 = fmaxf(v3,0.f); }
        pk.x = f2bf(v0); pk.y = f2bf(v1); pk.z = f2bf(v2); pk.w = f2bf(v3);
        *(ushort4*)(Xd + (kt << 11) + cp) = pk;
    }
}

// ============================ merged chain + post_self (post_self blocks FIRST) ============================
// __launch_bounds__(512, 4): min 4 waves/EU -> VGPR budget 128/wave. The chain tail
// keeps 3 A-frag sets (48 VGPR) + acc (16) + temps live; at the default budget the
// allocator spilled to scratch (rocprof showed 48-64 VGPR) — this lifts the cap.

__global__ __launch_bounds__(512, 4) void k_chainps(
    const float* __restrict__ key_feat, const float* __restrict__ cam_info,
    const float* __restrict__ key_pos, const float* __restrict__ Wk1,
    const unsigned short* __restrict__ wtU, const unsigned short* __restrict__ wxU,
    unsigned short* __restrict__ khH, unsigned short* __restrict__ vhH,
    const float* __restrict__ Wso, const float* __restrict__ Wcq,
    unsigned short* __restrict__ qwU,
    float* __restrict__ ws)
{
    __shared__ __align__(16) union SM {
        struct {
            unsigned short XA[8192];
            unsigned short XB[8192];
            float w1buf[256];
            float kpx[TK], kpy[TK];
            float cmu[NCAM], crs[NCAM];
        } c;
        struct {
            float sor[CC], qcr[CC], sq[CC];
            float part[4*132];
            float rs[CC], rs2[CC], col[2];
        } s;
    } sm;

    int t = threadIdx.x;

    if (blockIdx.x < NPS) {
        // ------------- post_self path (with fused self-attention) -------------
        int row = blockIdx.x;               // b*NQP + n
        int b = row / NQP, n = row - b*NQP;
        if (n >= NQ) { if (t < CC) qwU[(size_t)row*CC + t] = 0; return; }
        int rw = b*NQ + n;
        int d = t & 127, p = t >> 7;
        float* sor = sm.s.sor;
        float* qcr = sm.s.qcr;
        float* sq  = sm.s.sq;
        float* part = sm.s.part;
        float* rs = sm.s.rs;
        float* rs2 = sm.s.rs2;
        float* col = sm.s.col;

        if (t < CC) sq[t] = ws[O_SQ + (size_t)rw*CC + t];
        __syncthreads();

        // fused self-attn: head h = wave, keys lane-parallel
        {
            int h = t >> 6;       // 0..7
            int l = t & 63;
            float qv[16];
#pragma unroll
            for (int j = 0; j < 16; j++) qv[j] = sq[h*16 + j];
            float s[4], pexp[4];
            float mloc = -1e30f;
#pragma unroll
            for (int w2 = 0; w2 < 4; w2++) {
                int k = l + w2*64;
                float sv = -1e30f;
                if (k < NQ) {
                    const float* kr = ws + O_SK + ((size_t)(b*NQ + k))*CC + h*16;
                    float a2 = 0.f;
#pragma unroll
                    for (int j = 0; j < 16; j += 4) {
                        float4 kv = *(const float4*)(kr + j);
                        a2 += qv[j]*kv.x + qv[j+1]*kv.y + qv[j+2]*kv.z + qv[j+3]*kv.w;
                    }
                    sv = a2 * 0.25f;
                }
                s[w2] = sv;
                mloc = fmaxf(mloc, sv);
            }
#pragma unroll
            for (int off = 32; off > 0; off >>= 1) mloc = fmaxf(mloc, __shfl_xor(mloc, off));
            float lsum = 0.f;
#pragma unroll
            for (int w2 = 0; w2 < 4; w2++) {
                pexp[w2] = (s[w2] > -1e29f) ? __expf(s[w2] - mloc) : 0.f;
                lsum += pexp[w2];
            }
#pragma unroll
            for (int off = 32; off > 0; off >>= 1) lsum += __shfl_xor(lsum, off);
            float o[16];
#pragma unroll
            for (int j = 0; j < 16; j++) o[j] = 0.f;
#pragma unroll
            for (int w2 = 0; w2 < 4; w2++) {
                int k = l + w2*64;
                if (k < NQ) {
                    const float* vr = ws + O_SV + ((size_t)(b*NQ + k))*CC + h*16;
                    float pw = pexp[w2];
#pragma unroll
                    for (int j = 0; j < 16; j += 4) {
                        float4 vv = *(const float4*)(vr + j);
                        o[j]   = fmaf(pw, vv.x, o[j]);
                        o[j+1] = fmaf(pw, vv.y, o[j+1]);
                        o[j+2] = fmaf(pw, vv.z, o[j+2]);
                        o[j+3] = fmaf(pw, vv.w, o[j+3]);
                    }
                }
            }
#pragma unroll
            for (int j = 0; j < 16; j++) {
#pragma unroll
                for (int off = 32; off > 0; off >>= 1) o[j] += __shfl_xor(o[j], off);
            }
            if (l == 0) {
                float inv = 1.f / lsum;
#pragma unroll
                for (int j = 0; j < 16; j++) sor[h*16 + j] = o[j] * inv;
            }
        }
        __syncthreads();

        // Wso GEMV + LN + Wcq GEMV
        {
            float acc = 0.f;
            int c0 = p*32;
#pragma unroll
            for (int c = 0; c < 32; c++) acc = fmaf(sor[c0+c], Wso[(c0+c)*CC + d], acc);
            part[p*132 + d] = acc;
        }
        __syncthreads();
        float x = 0.f;
        if (t < CC) x = ws[O_Q0 + rw*CC + t] + ((part[t] + part[132+t]) + (part[264+t] + part[396+t]));
        x = lnorm512(x, t, rs, rs2, col);
        if (t < CC) {
            ws[O_X1 + rw*CC + t] = x;
            qcr[t] = x + ws[O_QPE + rw*CC + t];
        }
        __syncthreads();
        {
            float acc = 0.f;
            int c0 = p*32;
#pragma unroll
            for (int c = 0; c < 32; c++) acc = fmaf(qcr[c0+c], Wcq[(c0+c)*CC + d], acc);
            part[p*132 + d] = acc;
        }
        __syncthreads();
        if (t < CC) {
            float qh = (part[t] + part[132+t]) + (part[264+t] + part[396+t]);
            qwU[(size_t)row*CC + t] = f2bf(0.25f * LOG2E * qh);
        }
        return;
    }

    // ------------- chain path -------------
    unsigned short* XA = sm.c.XA;
    unsigned short* XB = sm.c.XB;
    float* w1buf = sm.c.w1buf;
    float* kpx = sm.c.kpx;
    float* kpy = sm.c.kpy;
    float* cmu = sm.c.cmu;
    float* crs = sm.c.crs;

    int blk = blockIdx.x - NPS;
    int b = blk / (KK/TK);
    int k0 = (blk - b*(KK/TK)) * TK;
    int l = t & 63;
    int m = l & 15, g = l >> 4;
    int w16 = t >> 6;                 // 0..7 = d-slice = head
    int dbase = w16 * 16;

    const unsigned short* WT_CW1  = wtU;
    const unsigned short* WT_CW2  = wtU + 4096;
    const unsigned short* WT_CW3  = wtU + 4096 + 16384;
    const unsigned short* WT_PROJ = wtU + 4096 + 2*16384;
    const unsigned short* WT_CK   = wtU + 4096 + 4*16384;
    const unsigned short* WT_CV   = wtU + 4096 + 5*16384;

    // cam_fin fused: recompute mu/rstd from the 256 partials
    if (t < NCAM) {
        float S = 0.f, S2 = 0.f;
#pragma unroll
        for (int bb2 = 0; bb2 < BB; bb2++)
#pragma unroll
            for (int s = 0; s < 8; s++) {
                int blk2 = ((bb2*NCAM + t) << 3) | s;
                S  += ws[O_CP + blk2*2];
                S2 += ws[O_CP + blk2*2 + 1];
            }
        float mu  = S * (1.0f/(BB*KK));
        float var = S2 * (1.0f/(BB*KK)) - mu*mu;
        cmu[t] = mu;
        crs[t] = rsqrtf(var + 1e-5f);
    }
    __syncthreads();

    if (t < 256) {
        // stage normalized cam -> XA (frag order): c = t>>4 in 0..15, 4 keys each
        int c = t >> 4;
        int kq = (t & 15) * 4;
        float4 v = *(const float4*)(cam_info + ((size_t)b*NCAM + c)*KK + k0 + kq);
        float mu = cmu[c], rsd = crs[c];
        int ktb = (kq >> 4) << 11;
        int cb  = frag_col(c & ~7, 0) + (c & 7);
        XA[ktb + cb + ((kq  ) & 15)*8] = f2bf((v.x - mu)*rsd);
        XA[ktb + cb + ((kq+1) & 15)*8] = f2bf((v.y - mu)*rsd);
        XA[ktb + cb + ((kq+2) & 15)*8] = f2bf((v.z - mu)*rsd);
        XA[ktb + cb + ((kq+3) & 15)*8] = f2bf((v.w - mu)*rsd);
        // zero cols 16..31
        {
            int z = t;
            int kt = z >> 6, r = z & 63;
            int gz = 2 + (r >> 5), mz = (r >> 1) & 15, j4 = (r & 1) * 4;
            ushort4 z4 = make_ushort4(0,0,0,0);
            *(ushort4*)(XA + (kt << 11) + (gz*16 + mz)*8 + j4) = z4;
        }
        w1buf[t] = Wk1[t];
    }
    if (t < TK) {
        float2 p = ((const float2*)key_pos)[b*KK + k0 + t];
        kpx[t] = p.x; kpy[t] = p.y;
    }

    // prologue A-frag loads: L1 + prefetch L2
    bfrag8 a1 = *(const bfrag8*)(WT_CW1 + (w16 << 9) + l*8);
    bfrag8 aA[4], aB[4], aC[4];
    ld_a4h(aA, WT_CW2, w16, l);
    __syncthreads();

    f32x4 acc[4];

    // L1: h1 = relu(cb @ cw1)
    mfma_apply1h(XA, a1, l, acc);
    store_tiles_h<true>(XB, acc, m, g, dbase);
    __syncthreads();
    ld_a4h(aB, WT_CW3, w16, l);          // prefetch L3

    // L2: h2 = relu(h1 @ cw2)
    mfma_apply4h(XB, aA, l, acc);
    store_tiles_h<true>(XA, acc, m, g, dbase);
    __syncthreads();
    ld_a4h(aA, WT_PROJ, w16, l);         // prefetch L4

    // stage key_feat -> XB (frag order, overlaps L3); L3: gate = sigmoid(h2 @ cw3)
    {
        int c = t >> 2, q4 = t & 3;
        const float* src = key_feat + ((size_t)b*CC + c)*KK + k0 + q4*16;
        int base = (q4 << 11) + frag_col(c & ~7, 0) + (c & 7);
#pragma unroll
        for (int qq = 0; qq < 4; qq++) {
            float4 v = ((const float4*)src)[qq];
            int mk = qq*4;
            XB[base + (mk  )*8] = f2bf(v.x);
            XB[base + (mk+1)*8] = f2bf(v.y);
            XB[base + (mk+2)*8] = f2bf(v.z);
            XB[base + (mk+3)*8] = f2bf(v.w);
        }
    }
    mfma_apply4h(XA, aB, l, acc);
    float garr[4][4];
#pragma unroll
    for (int kt = 0; kt < 4; kt++)
#pragma unroll
        for (int r = 0; r < 4; r++)
            garr[kt][r] = 1.f / (1.f + __expf(-acc[kt][r]));
    __syncthreads();
    ld_a4h(aB, WT_CK, w16, l);           // A-frags for kh (kf part)

    // L4: kf = (feat @ Wproj_k) * gate -> XA
    mfma_apply4h(XB, aA, l, acc);
#pragma unroll
    for (int kt = 0; kt < 4; kt++)
#pragma unroll
        for (int r = 0; r < 4; r++)
            acc[kt][r] *= garr[kt][r];
    store_tiles_h<false>(XA, acc, m, g, dbase);
    __syncthreads();
    ld_a4h(aA, WT_CV, w16, l);           // A-frags for vh
    ld_a4h(aC, wxU, w16, l);             // A-frags for kh (ph part, Wck2)

    // ph = relu(pos @ Wk_pos1) -> XB (frag order, two 16B stores per thread)
    {
        int k = t >> 3, dq = (t & 7) * 16;
        int ktb = (k >> 4) << 11;
        int mk = k & 15;
        float px = kpx[k], py = kpy[k];
        union { unsigned short u[8]; bfrag8 f; } cA, cB;
#pragma unroll
        for (int j = 0; j < 8; j++) {
            cA.u[j] = f2bf(fmaxf(px*w1buf[dq+j]   + py*w1buf[128+dq+j],   0.f));
            cB.u[j] = f2bf(fmaxf(px*w1buf[dq+8+j] + py*w1buf[128+dq+8+j], 0.f));
        }
        *(bfrag8*)(XB + ktb + frag_col(dq,     mk)) = cA.f;
        *(bfrag8*)(XB + ktb + frag_col(dq + 8, mk)) = cB.f;
    }
    __syncthreads();

    // FINAL fat phase (no more barriers): kh = kf@Wck + ph@Wck2 ; vh = kf@Wcv
    mfma_apply4h(XA, aB, l, acc);        // kf @ Wck
    mfma_acc4h(XB, aC, l, acc);          // += ph @ Wck2
#pragma unroll
    for (int kt = 0; kt < 4; kt++) {
        int k = k0 + kt*16 + m;
        ushort4 pk;
        pk.x = f2bf(acc[kt][0]); pk.y = f2bf(acc[kt][1]);
        pk.z = f2bf(acc[kt][2]); pk.w = f2bf(acc[kt][3]);
        *(ushort4*)(khH + (((size_t)(b*NH + w16)*KK + k) << 4) + g*4) = pk;
    }
    mfma_apply4h(XA, aA, l, acc);        // kf @ Wcv
#pragma unroll
    for (int kt = 0; kt < 4; kt++) {
        int k = k0 + kt*16 + m;
        size_t tb = ((size_t)(b*NH + w16)*(KK/32) + (k >> 5))*512 + (k & 31);
#pragma unroll
        for (int r = 0; r < 4; r++)
            vhH[tb + (g*4 + r)*32] = f2bf(acc[kt][r]);
    }
}

// ============================ MFMA flash cross-attention ============================

struct KPRegs { float4 r[8]; };

__device__ __forceinline__ void kp_read(KPRegs& kp, const float4* __restrict__ f4, int fb) {
#pragma unroll
    for (int mm = 0; mm < 4; mm++) {
        kp.r[2*mm]   = f4[fb + 4*mm];
        kp.r[2*mm+1] = f4[fb + 4*mm + 1];
    }
}
__device__ __forceinline__ void kp_bias(f32x16& bias, const KPRegs& kp,
                                        float qx, float qy, float nsx, float nsy) {
#pragma unroll
    for (int mm = 0; mm < 4; mm++) {
        float4 c0 = kp.r[2*mm], c1 = kp.r[2*mm+1];
        float dx, dy;
        dx = c0.x - qx; dy = c0.y - qy; bias[4*mm+0] = fmaf(dy*dy, nsy, dx*dx*nsx);
        dx = c0.z - qx; dy = c0.w - qy; bias[4*mm+1] = fmaf(dy*dy, nsy, dx*dx*nsx);
        dx = c1.x - qx; dy = c1.y - qy; bias[4*mm+2] = fmaf(dy*dy, nsy, dx*dx*nsx);
        dx = c1.z - qx; dy = c1.w - qy; bias[4*mm+3] = fmaf(dy*dy, nsy, dx*dx*nsx);
    }
}

__device__ __forceinline__ void flash_head(
    const f32x16& s, f32x16& acc, bfrag8 vfa, bfrag8 vfb)
{
    float p[16];
#pragma unroll
    for (int i = 0; i < 16; i++) p[i] = EXP2(s[i]);
    unsigned pk[8];
#pragma unroll
    for (int mm = 0; mm < 4; mm++) {
        pk[2*mm]   = cvtpk_bf16(p[4*mm],   p[4*mm+1]);
        pk[2*mm+1] = cvtpk_bf16(p[4*mm+2], p[4*mm+3]);
    }
    {
        unsigned a0 = pk[0], b0 = pk[2];
        unsigned a1 = pk[1], b1 = pk[3];
        pl32swap(a0, b0);
        pl32swap(a1, b1);
        union { unsigned u[4]; bfrag8 f; } pf;
        pf.u[0] = a0; pf.u[1] = a1; pf.u[2] = b0; pf.u[3] = b1;
        acc = __builtin_amdgcn_mfma_f32_32x32x16_bf16(vfa, pf.f, acc, 0, 0, 0);
    }
    {
        unsigned a0 = pk[4], b0 = pk[6];
        unsigned a1 = pk[5], b1 = pk[7];
        pl32swap(a0, b0);
        pl32swap(a1, b1);
        union { unsigned u[4]; bfrag8 f; } pf;
        pf.u[0] = a0; pf.u[1] = a1; pf.u[2] = b0; pf.u[3] = b1;
        acc = __builtin_amdgcn_mfma_f32_32x32x16_bf16(vfb, pf.f, acc, 0, 0, 0);
    }
}

__global__ __launch_bounds__(256) void k_flash(
    const float* __restrict__ qpos, const float* __restrict__ key_pos,
    const unsigned short* __restrict__ khH, const unsigned short* __restrict__ vhH,
    const unsigned short* __restrict__ qwU, const unsigned short* __restrict__ onesU,
    float* __restrict__ ws)
{
    // XCD-group swizzle: SLOTX groups per XCD
    int id = blockIdx.x;
    int slot = id >> 3;
    int group = (id & 7) * SLOTX + slot / 7;
    if (group >= NGRP) return;
    int qt  = slot % 7;
    int b   = group / NSEG;
    int seg = group - b*NSEG;

    int wv  = threadIdx.x >> 6;
    int l   = threadIdx.x & 63;
    int lq  = l & 31;
    int g   = l >> 5;
    int h0  = wv*2, h1 = h0 + 1;
    int q   = qt*32 + lq;
    int qc  = min(q, NQ-1);
    int t   = threadIdx.x;

    __shared__ __align__(16) float kpbuf[TPS*32*2];

    int kt0 = seg * (TPS*32);
    {
        const float4* src = (const float4*)(key_pos + ((size_t)b*KK + kt0)*2);
        for (int i = t; i < TPS*32/2; i += 256)
            ((float4*)kpbuf)[i] = src[i];
    }

    float qx  = qpos[(b*NQ+qc)*2], qy = qpos[(b*NQ+qc)*2+1];
    float nsx = -ws[O_SINV + (b*NQ+qc)*2];
    float nsy = -ws[O_SINV + (b*NQ+qc)*2+1];

    const unsigned short* qrow = qwU + ((size_t)b*NQP + q)*CC + g*8;
    bfrag8 qf0 = *(const bfrag8*)(qrow + h0*DH);
    bfrag8 qf1 = *(const bfrag8*)(qrow + h1*DH);

    const unsigned short* kb0 = khH + (((size_t)(b*NH + h0)*KK + lq) << 4) + g*8;
    const unsigned short* kb1 = khH + (((size_t)(b*NH + h1)*KK + lq) << 4) + g*8;
    bool isOnes = (lq == 16);
    const unsigned short* vt0 = vhH + (size_t)(b*NH + h0)*(KK/32)*512 + (lq & 15)*32 + g*8;
    const unsigned short* vt1 = vhH + (size_t)(b*NH + h1)*(KK/32)*512 + (lq & 15)*32 + g*8;
    const unsigned short* on8 = onesU + g*8;

    f32x16 acc0, acc1;
#pragma unroll
    for (int i = 0; i < 16; i++) { acc0[i] = 0.f; acc1[i] = 0.f; }

    int tile0 = kt0 >> 5;
    bfrag8 kf0 = *(const bfrag8*)(kb0 + ((size_t)kt0 << 4));
    bfrag8 kf1 = *(const bfrag8*)(kb1 + ((size_t)kt0 << 4));
    bfrag8 vc00 = isOnes ? *(const bfrag8*)on8 : *(const bfrag8*)(vt0 + (size_t)tile0*512);
    bfrag8 vc01 = isOnes ? *(const bfrag8*)on8 : *(const bfrag8*)(vt0 + (size_t)tile0*512 + 16);
    bfrag8 vc10 = isOnes ? *(const bfrag8*)on8 : *(const bfrag8*)(vt1 + (size_t)tile0*512);
    bfrag8 vc11 = isOnes ? *(const bfrag8*)on8 : *(const bfrag8*)(vt1 + (size_t)tile0*512 + 16);

    __syncthreads();

    const float4* kpf4 = (const float4*)kpbuf;
    KPRegs kpn;
    kp_read(kpn, kpf4, 2*g);
    f32x16 bias;
    kp_bias(bias, kpn, qx, qy, nsx, nsy);

    for (int it = 0; it < TPS; it++) {
        int itn = (it+1 < TPS) ? it+1 : it;
        int kn = kt0 + itn*32;
        int tn = kn >> 5;
        bfrag8 kf0n = *(const bfrag8*)(kb0 + ((size_t)kn << 4));
        bfrag8 kf1n = *(const bfrag8*)(kb1 + ((size_t)kn << 4));
        bfrag8 vn00 = isOnes ? *(const bfrag8*)on8 : *(const bfrag8*)(vt0 + (size_t)tn*512);
        bfrag8 vn01 = isOnes ? *(const bfrag8*)on8 : *(const bfrag8*)(vt0 + (size_t)tn*512 + 16);
        bfrag8 vn10 = isOnes ? *(const bfrag8*)on8 : *(const bfrag8*)(vt1 + (size_t)tn*512);
        bfrag8 vn11 = isOnes ? *(const bfrag8*)on8 : *(const bfrag8*)(vt1 + (size_t)tn*512 + 16);
        kp_read(kpn, kpf4, itn*16 + 2*g);

        f32x16 s0 = __builtin_amdgcn_mfma_f32_32x32x16_bf16(kf0, qf0, bias, 0, 0, 0);
        f32x16 s1 = __builtin_amdgcn_mfma_f32_32x32x16_bf16(kf1, qf1, bias, 0, 0, 0);

        flash_head(s0, acc0, vc00, vc01);
        flash_head(s1, acc1, vc10, vc11);

        kp_bias(bias, kpn, qx, qy, nsx, nsy);
        kf0 = kf0n; kf1 = kf1n;
        vc00 = vn00; vc01 = vn01; vc10 = vn10; vc11 = vn11;
    }

    {
        float* o = ws + O_PART + (((size_t)(b*NH + h0)*NSEG + seg)*NQP + q)*18;
        if (l < 32) o[0] = acc0[8];
#pragma unroll
        for (int rr = 0; rr < 8; rr++) o[1 + (rr&3) + 8*(rr>>2) + 4*g] = acc0[rr];
    }
    {
        float* o = ws + O_PART + (((size_t)(b*NH + h1)*NSEG + seg)*NQP + q)*18;
        if (l < 32) o[0] = acc1[8];
#pragma unroll
        for (int rr = 0; rr < 8; rr++) o[1 + (rr&3) + 8*(rr>>2) + 4*g] = acc1[rr];
    }
}

// ============================ combine + Wco + LN + FFN + LN (fused, 512-thr seg-split) ============================

__global__ __launch_bounds__(512) void k_final(
    const float* __restrict__ Wco, const float* __restrict__ W1,
    const float* __restrict__ b1f, const float* __restrict__ W2,
    const float* __restrict__ b2f, float* __restrict__ ws,
    float* __restrict__ out)
{
    int row = blockIdx.x;               // b*NQ + q
    int b = row / NQ, q = row - b*NQ;
    int t = threadIdx.x;
    int d = t & 127, p = t >> 7;
    __shared__ float orow[CC], x1r[CC], x2r[CC], hrr[NFFN];
    __shared__ float part[4*132];
    __shared__ float part2[2*260];
    __shared__ float rs[CC], rs2[CC], col[2];
    __shared__ float lpart[32], Lh[8];

    // combine: 4-way seg-split sums over PART (fixed-max softmax => plain sums)
    {
        int h = d >> 4, j = d & 15;
        const float* pb = ws + O_PART + (((size_t)(b*NH + h)*NSEG)*NQP + q)*18;
        int s0 = p*13, s1 = (s0 + 13 < NSEG) ? s0 + 13 : NSEG;
        float sA = 0.f, sL = 0.f;
        for (int sg = s0; sg < s1; sg++) {
            const float* pp = pb + (size_t)sg*(NQP*18);
            sA += pp[1 + j];
            if (j == 0) sL += pp[0];
        }
        part[p*132 + d] = sA;
        if (j == 0) lpart[p*8 + h] = sL;
    }
    if (t < CC) x1r[t] = ws[O_X1 + (size_t)row*CC + t];
    __syncthreads();
    if (t < 8) Lh[t] = (lpart[t] + lpart[8+t]) + (lpart[16+t] + lpart[24+t]);
    __syncthreads();
    if (t < CC)
        orow[t] = ((part[t] + part[132+t]) + (part[264+t] + part[396+t])) / Lh[t >> 4];
    __syncthreads();

    {
        float acc = 0.f;
        int c0 = p*32;
#pragma unroll
        for (int c = 0; c < 32; c++) acc = fmaf(orow[c0+c], Wco[(c0+c)*CC + d], acc);
        part[p*132 + d] = acc;
    }
    __syncthreads();
    float x = 0.f;
    if (t < CC) x = x1r[t] + ((part[t] + part[132+t]) + (part[264+t] + part[396+t]));
    x = lnorm512(x, t, rs, rs2, col);
    if (t < CC) x2r[t] = x;
    __syncthreads();
    {
        int o = t & 255, ph2 = t >> 8;
        float h = 0.f;
        int c0 = ph2*64;
#pragma unroll 16
        for (int c = 0; c < 64; c++) h = fmaf(x2r[c0+c], W1[(c0+c)*NFFN + o], h);
        part2[ph2*260 + o] = h;
    }
    __syncthreads();
    if (t < NFFN) hrr[t] = fmaxf(part2[t] + part2[260+t] + b1f[t], 0.f);
    __syncthreads();
    {
        float acc = 0.f;
        int f0 = p*64;
#pragma unroll 16
        for (int f = 0; f < 64; f++) acc = fmaf(hrr[f0+f], W2[(f0+f)*CC + d], acc);
        part[p*132 + d] = acc;
    }
    __syncthreads();
    float y = 0.f;
    if (t < CC) y = x2r[t] + b2f[t] + ((part[t] + part[132+t]) + (part[264+t] + part[396+t]));
    y = lnorm512(y, t, rs, rs2, col);
    if (t < CC) out[(size_t)row*CC + t] = y;
}

// ============================ launch ============================

extern "C" void kernel_launch(void* const* d_in, const int* in_sizes, int n_in,
                              void* d_out, int out_size, void* d_ws, size_t ws_size,
                              hipStream_t stream)
{
    const float* query_feat = (const float*)d_in[0];
    const float* key_feat   = (const float*)d_in[1];
    const float* query_pos  = (const float*)d_in[2];
    const float* key_pos    = (const float*)d_in[3];
    const float* query_size = (const float*)d_in[4];
    const float* cam_info   = (const float*)d_in[5];
    const float* Wproj_q = (const float*)d_in[6];
    const float* Wproj_k = (const float*)d_in[7];
    const float* Wq_pos1 = (const float*)d_in[8];
    const float* Wq_pos2 = (const float*)d_in[9];
    const float* Wk_pos1 = (const float*)d_in[10];
    const float* Wk_pos2 = (const float*)d_in[11];
    const float* Wsq = (const float*)d_in[12];
    const float* Wsk = (const float*)d_in[13];
    const float* Wsv = (const float*)d_in[14];
    const float* Wso = (const float*)d_in[15];
    const float* Wcq = (const float*)d_in[16];
    const float* Wck = (const float*)d_in[17];
    const float* Wcv = (const float*)d_in[18];
    const float* Wco = (const float*)d_in[19];
    const float* Wffn1 = (const float*)d_in[20];
    const float* bffn1 = (const float*)d_in[21];
    const float* Wffn2 = (const float*)d_in[22];
    const float* bffn2 = (const float*)d_in[23];
    const float* cam_w1 = (const float*)d_in[24];
    const float* cam_w2 = (const float*)d_in[25];
    const float* cam_w3 = (const float*)d_in[26];
    float* ws  = (float*)d_ws;
    float* out = (float*)d_out;
    unsigned short* wsu = (unsigned short*)(ws + O_BF);
    unsigned short* khH = wsu + U_KH;
    unsigned short* vhH = wsu + U_VH;
    unsigned short* wtU = wsu + U_W;
    unsigned short* qwU = wsu + U_QW;
    unsigned short* onU = wsu + U_ONES;
    unsigned short* wxU = wsu + U_WX;

    hipLaunchKernelGGL(k_pre, dim3(264 + NQB + 8), dim3(512), 0, stream,
        cam_info, cam_w2, cam_w3, Wproj_k, Wk_pos2, Wck, Wcv, cam_w1, wtU, onU, wxU, ws,
        query_feat, query_pos, query_size, Wproj_q, Wq_pos1, Wq_pos2, Wsq, Wsk, Wsv);
    hipLaunchKernelGGL(k_chainps, dim3(NPS + BB*KK/TK), dim3(512), 0, stream,
        key_feat, cam_info, key_pos, Wk_pos1, wtU, wxU, khH, vhH, Wso, Wcq, qwU, ws);
    hipLaunchKernelGGL(k_flash, dim3(8*SLOTX*7), dim3(256), 0, stream,
        query_pos, key_pos, khH, vhH, qwU, onU, ws);
    hipLaunchKernelGGL(k_final, dim3(BB*NQ), dim3(512), 0, stream,
        Wco, Wffn1, bffn1, Wffn2, bffn2, ws, out);
}